// Round 14
// baseline (184.596 us; speedup 1.0000x reference)
//
#include <hip/hip_runtime.h>
#include <hip/hip_bf16.h>

#define NQ      10
#define NLAYERS 4
#define D_IN    784
#define BLOCK   64             // ONE wave per workgroup; R14: each wave simulates FOUR states.
#define NS      4              // R12 (2 states) was compressed to 64 VGPR by the RA via AGPR
                               // round-trips (accvgpr moves ate the ILP). 128 amp regs make
                               // that tier impossible -> real VGPRs + 4 independent chains.
// LOCKED: waves_per_eu(2,8). Occupancy floor >=4 waves/EU (launch_bounds(.,4),
// waves_per_eu(4,8), BLOCK=1024) forces 64 VGPRs + scratch spill: 760+ MB HBM writes,
// +120-190 us (R3/R5/R7). Healthy kernel: WRITE_SIZE ~0.4 MB, FETCH ~13 MB.
// LOCKED: reductions use plain __shfl_xor only (R8: DPP/Walsh/readlane reductions diverged
// nondeterministically across graph replays). DPP only in full-exec gate code (stable since R4).
// LOCKED: no permlane16/32_swap XOR-emulation (R13: +1.5k VALU inst on the busier pipe, -5%).
// R11 packed f2 math: 209->171. R12 2-state ILP: ->166. R13 permlane: 174 (reverted).

// Amplitude index i (10 bits): i = lane(6 bits, i[9:4]) * 16 + r(4 bits, i[3:0]).
// Qubit q sits at bit P = 9-q.  P>=4 -> lane qubit (lane bit P-4), P<4 -> register qubit.

typedef __attribute__((ext_vector_type(2))) float f2;

__device__ __forceinline__ f2 cswapneg(f2 v) {   // i * v = (-im, re)
    f2 r; r.x = -v.y; r.y = v.x; return r;
}

template<int LB>
__device__ __forceinline__ float lane_xor(float v) {
    if constexpr (LB == 1) {        // quad_perm [1,0,3,2] — VALU (DPP)
        return __int_as_float(__builtin_amdgcn_update_dpp(
            0, __float_as_int(v), 0xB1, 0xF, 0xF, false));
    } else if constexpr (LB == 2) { // quad_perm [2,3,0,1] — VALU (DPP)
        return __int_as_float(__builtin_amdgcn_update_dpp(
            0, __float_as_int(v), 0x4E, 0xF, 0xF, false));
    } else {
        return __shfl_xor(v, LB, 64);   // masks 4..32 -> DS pipe
    }
}

template<int LB>
__device__ __forceinline__ f2 lane_xor2(f2 v) {
    f2 r; r.x = lane_xor<LB>(v.x); r.y = lane_xor<LB>(v.y); return r;
}

// ---- generic complex 2x2 gate (Rot) on bit position P, NS states interleaved ----
template<int P>
__device__ __forceinline__ void rot_gateN(f2 (&a)[NS][16], int lane, float4 gA, float4 gB) {
    if constexpr (P >= 4) {
        const int lb = 1 << (P - 4);
        const bool hi = (lane & lb) != 0;
        const float gdx = hi ? gB.z : gA.x, gdy = hi ? gB.w : gA.y;   // diagonal
        const float gox = hi ? gB.x : gA.z, goy = hi ? gB.y : gA.w;   // off-diagonal
#pragma unroll
        for (int r = 0; r < 16; r++) {
#pragma unroll
            for (int s = 0; s < NS; s++) {
                f2 o = lane_xor2<lb>(a[s][r]);
                f2 v = a[s][r];
                a[s][r] = gdx * v + gdy * cswapneg(v) + gox * o + goy * cswapneg(o);
            }
        }
    } else {
        const int m = 1 << P;
#pragma unroll
        for (int r = 0; r < 16; r++) {
            if (!(r & m)) {
                const int r1 = r | m;
#pragma unroll
                for (int s = 0; s < NS; s++) {
                    f2 A0 = a[s][r], A1 = a[s][r1];
                    f2 i0 = cswapneg(A0), i1 = cswapneg(A1);
                    a[s][r]  = gA.x * A0 + gA.y * i0 + gA.z * A1 + gA.w * i1;
                    a[s][r1] = gB.x * A0 + gB.y * i0 + gB.z * A1 + gB.w * i1;
                }
            }
        }
    }
}

// ---- layer-0 variant: per-state matrices (RY fused, angles differ per state) ----
template<int P>
__device__ __forceinline__ void rot_gateN_ab(f2 (&a)[NS][16], int lane,
                                             const float4 (&mA)[NS], const float4 (&mB)[NS]) {
    if constexpr (P >= 4) {
        const int lb = 1 << (P - 4);
        const bool hi = (lane & lb) != 0;
        float gdx[NS], gdy[NS], gox[NS], goy[NS];
#pragma unroll
        for (int s = 0; s < NS; s++) {
            gdx[s] = hi ? mB[s].z : mA[s].x;  gdy[s] = hi ? mB[s].w : mA[s].y;
            gox[s] = hi ? mB[s].x : mA[s].z;  goy[s] = hi ? mB[s].y : mA[s].w;
        }
#pragma unroll
        for (int r = 0; r < 16; r++) {
#pragma unroll
            for (int s = 0; s < NS; s++) {
                f2 o = lane_xor2<lb>(a[s][r]);
                f2 v = a[s][r];
                a[s][r] = gdx[s] * v + gdy[s] * cswapneg(v) + gox[s] * o + goy[s] * cswapneg(o);
            }
        }
    } else {
        const int m = 1 << P;
#pragma unroll
        for (int r = 0; r < 16; r++) {
            if (!(r & m)) {
                const int r1 = r | m;
#pragma unroll
                for (int s = 0; s < NS; s++) {
                    f2 A0 = a[s][r], A1 = a[s][r1];
                    f2 i0 = cswapneg(A0), i1 = cswapneg(A1);
                    a[s][r]  = mA[s].x * A0 + mA[s].y * i0 + mA[s].z * A1 + mA[s].w * i1;
                    a[s][r1] = mB[s].x * A0 + mB[s].y * i0 + mB[s].z * A1 + mB[s].w * i1;
                }
            }
        }
    }
}

// ---- rot<9> with the PREVIOUS layer's CNOT(ctrl=reg bit0, tgt=lane bit 32) fused in ----
__device__ __forceinline__ void rot9_fusedN(f2 (&a)[NS][16], int lane, float4 gA, float4 gB) {
    const bool hi = (lane & 32) != 0;
    const float gdx = hi ? gB.z : gA.x, gdy = hi ? gB.w : gA.y;
    const float gox = hi ? gB.x : gA.z, goy = hi ? gB.y : gA.w;
#pragma unroll
    for (int r = 0; r < 16; r++) {
#pragma unroll
        for (int s = 0; s < NS; s++) {
            f2 o = lane_xor2<32>(a[s][r]);
            f2 v = a[s][r];
            if (!(r & 1)) {
                a[s][r] = gdx * v + gdy * cswapneg(v) + gox * o + goy * cswapneg(o);
            } else {   // fused CNOT: own/partner roles swapped
                a[s][r] = gdx * o + gdy * cswapneg(o) + gox * v + goy * cswapneg(v);
            }
        }
    }
}

// ---- CNOT on all states: control bit PC, target bit PT ----
template<int PC, int PT>
__device__ __forceinline__ void cnot_gateN(f2 (&a)[NS][16], int lane) {
    if constexpr (PC >= 4 && PT < 4) {                // lane control, register target
        const int mt = 1 << PT;
        const bool ctl = (lane & (1 << (PC - 4))) != 0;
#pragma unroll
        for (int r = 0; r < 16; r++) {
            if (!(r & mt)) {
                const int r1 = r | mt;
#pragma unroll
                for (int s = 0; s < NS; s++) {
                    f2 A0 = a[s][r], A1 = a[s][r1];
                    f2 n0, n1;
                    n0.x = ctl ? A1.x : A0.x;  n0.y = ctl ? A1.y : A0.y;
                    n1.x = ctl ? A0.x : A1.x;  n1.y = ctl ? A0.y : A1.y;
                    a[s][r] = n0; a[s][r1] = n1;
                }
            }
        }
    } else if constexpr (PC < 4 && PT >= 4) {         // register control, lane target
        const int mc = 1 << PC, mt = 1 << (PT - 4);
#pragma unroll
        for (int r = 0; r < 16; r++) {
            if (r & mc) {
#pragma unroll
                for (int s = 0; s < NS; s++) {
                    a[s][r].x = __shfl_xor(a[s][r].x, mt, 64);
                    a[s][r].y = __shfl_xor(a[s][r].y, mt, 64);
                }
            }
        }
    } else {                                          // register-register: free rename
        const int mc = 1 << PC, mt = 1 << PT;
#pragma unroll
        for (int r = 0; r < 16; r++) {
            if ((r & mc) && !(r & mt)) {
                const int r1 = r | mt;
#pragma unroll
                for (int s = 0; s < NS; s++) {
                    f2 t = a[s][r]; a[s][r] = a[s][r1]; a[s][r1] = t;
                }
            }
        }
    }
}

__global__ __launch_bounds__(BLOCK)
__attribute__((amdgpu_waves_per_eu(2, 8)))
void qnet_kernel(
    const float* __restrict__ x,
    const float* __restrict__ Wp,
    const float* __restrict__ bp,
    const float* __restrict__ qw,
    const float* __restrict__ Wo,
    const float* __restrict__ bo,
    float* __restrict__ out, int B)
{
    __shared__ __align__(16) float gates[NLAYERS * NQ * 8];  // per-wave Rot matrix table

    const int lane = threadIdx.x;        // single wave per block
    const int s0   = blockIdx.x * NS;    // this wave's NS states

    // ---- Rot gate table (single wave: barrier is intra-wave, ~free) ----
    if (lane < NLAYERS * NQ) {
        float phi = qw[lane * 3 + 0];
        float th  = qw[lane * 3 + 1];
        float om  = qw[lane * 3 + 2];
        float s, c;   sincosf(0.5f * th, &s, &c);
        float sap, cap; sincosf(0.5f * (phi + om), &sap, &cap);
        float sam, cam; sincosf(0.5f * (phi - om), &sam, &cam);
        float* g = &gates[lane * 8];
        g[0] =  cap * c;  g[1] = -sap * c;   // u00
        g[2] = -cam * s;  g[3] = -sam * s;   // u01
        g[4] =  cam * s;  g[5] = -sam * s;   // u10
        g[6] =  cap * c;  g[7] =  sap * c;   // u11
    }
    __syncthreads();
    if (s0 >= B) return;

    // ---- projection for NS states (Wp value shared across states) ----
    float acc[NS][NQ];
#pragma unroll
    for (int s = 0; s < NS; s++)
#pragma unroll
        for (int q = 0; q < NQ; q++) acc[s][q] = 0.f;
    for (int d = lane; d < D_IN; d += 64) {
        float xv[NS];
#pragma unroll
        for (int s = 0; s < NS; s++) xv[s] = x[(size_t)(s0 + s) * D_IN + d];
#pragma unroll
        for (int q = 0; q < NQ; q++) {
            float w = Wp[q * D_IN + d];
#pragma unroll
            for (int s = 0; s < NS; s++) acc[s][q] += xv[s] * w;
        }
    }
#pragma unroll
    for (int s = 0; s < NS; s++)
#pragma unroll
        for (int q = 0; q < NQ; q++) {
#pragma unroll
            for (int o = 1; o < 64; o <<= 1) acc[s][q] += __shfl_xor(acc[s][q], o, 64);
        }
    float myc[NS], mys[NS];
#pragma unroll
    for (int s = 0; s < NS; s++) { myc[s] = 1.f; mys[s] = 0.f; }
    if (lane < NQ) {
#pragma unroll
        for (int s = 0; s < NS; s++) {
            float h = tanhf(acc[s][lane] + bp[lane]);
            sincosf(0.5f * h, &mys[s], &myc[s]);
        }
    }

    // ---- statevectors |0..0> in registers, packed (re,im) ----
    f2 a[NS][16];
#pragma unroll
    for (int s = 0; s < NS; s++)
#pragma unroll
        for (int r = 0; r < 16; r++) { a[s][r].x = 0.f; a[s][r].y = 0.f; }
    if (lane == 0) {
#pragma unroll
        for (int s = 0; s < NS; s++) a[s][0].x = 1.f;
    }

    // Pull-index for the composite lane-CNOT chain: src_lane = Gray(lane)
    const int bidx = (lane ^ (lane >> 1)) << 2;

    // ---- layer 0: RY fused into Rot (per-state matrices) ----
    {
        const float* gl = &gates[0];
#define FROTQ(Q) \
        { float4 gA = *(const float4*)(gl + Q * 8); \
          float4 gB = *(const float4*)(gl + Q * 8 + 4); \
          float4 mA[NS], mB[NS]; \
          _Pragma("unroll") \
          for (int s = 0; s < NS; s++) { \
            float c = __shfl(myc[s], Q, 64), ss = __shfl(mys[s], Q, 64); \
            mA[s].x = gA.x * c + gA.z * ss;  mA[s].y = gA.y * c + gA.w * ss; \
            mA[s].z = gA.z * c - gA.x * ss;  mA[s].w = gA.w * c - gA.y * ss; \
            mB[s].x = gB.x * c + gB.z * ss;  mB[s].y = gB.y * c + gB.w * ss; \
            mB[s].z = gB.z * c - gB.x * ss;  mB[s].w = gB.w * c - gB.y * ss; \
          } \
          rot_gateN_ab<9 - Q>(a, lane, mA, mB); }
        FROTQ(0) FROTQ(1) FROTQ(2) FROTQ(3) FROTQ(4)
        FROTQ(5) FROTQ(6) FROTQ(7) FROTQ(8) FROTQ(9)
#undef FROTQ
        // CNOT ring (9,8)..(5,4) as one lane permutation, all states
#pragma unroll
        for (int r = 0; r < 16; r++) {
#pragma unroll
            for (int s = 0; s < NS; s++) {
                a[s][r].x = __int_as_float(__builtin_amdgcn_ds_bpermute(bidx, __float_as_int(a[s][r].x)));
                a[s][r].y = __int_as_float(__builtin_amdgcn_ds_bpermute(bidx, __float_as_int(a[s][r].y)));
            }
        }
        cnot_gateN<4, 3>(a, lane);
        cnot_gateN<3, 2>(a, lane);
        cnot_gateN<2, 1>(a, lane);
        cnot_gateN<1, 0>(a, lane);
        // cnot<0,9> fused into next layer's rot<9>
    }

    // ---- layers 1..3 (first gate consumes previous layer's trailing cnot<0,9>) ----
    for (int l = 1; l < NLAYERS; l++) {
        const float* gl = &gates[l * NQ * 8];
        {   float4 gA = *(const float4*)(gl);
            float4 gB = *(const float4*)(gl + 4);
            rot9_fusedN(a, lane, gA, gB); }
#define ROTQ(Q) { float4 gA = *(const float4*)(gl + Q * 8); \
                  float4 gB = *(const float4*)(gl + Q * 8 + 4); \
                  rot_gateN<9 - Q>(a, lane, gA, gB); }
        ROTQ(1) ROTQ(2) ROTQ(3) ROTQ(4)
        ROTQ(5) ROTQ(6) ROTQ(7) ROTQ(8) ROTQ(9)
#undef ROTQ
#pragma unroll
        for (int r = 0; r < 16; r++) {
#pragma unroll
            for (int s = 0; s < NS; s++) {
                a[s][r].x = __int_as_float(__builtin_amdgcn_ds_bpermute(bidx, __float_as_int(a[s][r].x)));
                a[s][r].y = __int_as_float(__builtin_amdgcn_ds_bpermute(bidx, __float_as_int(a[s][r].y)));
            }
        }
        cnot_gateN<4, 3>(a, lane);
        cnot_gateN<3, 2>(a, lane);
        cnot_gateN<2, 1>(a, lane);
        cnot_gateN<1, 0>(a, lane);
    }
    // layer 3's trailing cnot<0,9> applied for real (measurement follows)
    cnot_gateN<0, 9>(a, lane);

    // ---- measurement: Z expectation per qubit, all states ----
    float zq[NS][NQ];
#pragma unroll
    for (int s = 0; s < NS; s++) {
        float S = 0.f, z3 = 0.f, z2 = 0.f, z1 = 0.f, z0 = 0.f;
#pragma unroll
        for (int r = 0; r < 16; r++) {
            float p = a[s][r].x * a[s][r].x + a[s][r].y * a[s][r].y;
            S += p;
            z3 += (r & 8) ? -p : p;
            z2 += (r & 4) ? -p : p;
            z1 += (r & 2) ? -p : p;
            z0 += (r & 1) ? -p : p;
        }
        zq[s][6] = z3; zq[s][7] = z2; zq[s][8] = z1; zq[s][9] = z0;   // register qubits
#pragma unroll
        for (int q = 0; q < 6; q++)                                    // lane qubits: bit 5-q
            zq[s][q] = ((lane >> (5 - q)) & 1) ? -S : S;
    }
#pragma unroll
    for (int s = 0; s < NS; s++)
#pragma unroll
        for (int q = 0; q < NQ; q++) {
#pragma unroll
            for (int o = 1; o < 64; o <<= 1) zq[s][q] += __shfl_xor(zq[s][q], o, 64);
        }

    // ---- output projection: out = zq @ Wo^T + bo, all states ----
    if (lane < NQ) {
        const float* wrow = Wo + lane * NQ;
        float bb = bo[lane];
#pragma unroll
        for (int s = 0; s < NS; s++) {
            float o = bb;
#pragma unroll
            for (int q = 0; q < NQ; q++) o += zq[s][q] * wrow[q];
            out[(size_t)(s0 + s) * NQ + lane] = o;
        }
    }
}

extern "C" void kernel_launch(void* const* d_in, const int* in_sizes, int n_in,
                              void* d_out, int out_size, void* d_ws, size_t ws_size,
                              hipStream_t stream) {
    const float* x  = (const float*)d_in[0];
    const float* Wp = (const float*)d_in[1];
    const float* bp = (const float*)d_in[2];
    const float* qw = (const float*)d_in[3];
    const float* Wo = (const float*)d_in[4];
    const float* bo = (const float*)d_in[5];
    float* out = (float*)d_out;

    const int B = in_sizes[0] / D_IN;                    // 8192 states, NS per wave/block
    const int blocks = (B + NS - 1) / NS;
    hipLaunchKernelGGL(qnet_kernel, dim3(blocks), dim3(BLOCK), 0, stream,
                       x, Wp, bp, qw, Wo, bo, out, B);
}